// Round 6
// baseline (241.034 us; speedup 1.0000x reference)
//
#include <hip/hip_runtime.h>

// ComplexMixture: B=32, S=8192, D=64, fp32 in/out.
// out_real = (R^T R + I^T I)/S ; out_imag = (R^T I - (R^T I)^T)/S
// R6: TLP attack. All five prior rounds fit one model: ~1 memory request in
// flight per wave regardless of structure => throughput = waves * req_size /
// latency. So: 16 waves/CU (4 blocks/CU, 33.3 KB LDS) and 32 x 1KB DMAs per
// wave. Wave-private single-buffer staging, no main-loop barriers.

#define BATCH  32
#define SEQ    8192
#define DD     64

typedef __bf16 bf16x8 __attribute__((ext_vector_type(8)));
typedef float  f32x16 __attribute__((ext_vector_type(16)));

#define GLD_LDS16(gp, lp) \
  __builtin_amdgcn_global_load_lds( \
      (const __attribute__((address_space(1))) void*)(gp), \
      (__attribute__((address_space(3))) void*)(lp), 16, 0, 0)

__device__ __forceinline__ unsigned bf16pk(float a, float b) {
  unsigned ua = __builtin_bit_cast(unsigned, a);
  unsigned ub = __builtin_bit_cast(unsigned, b);
  ua = (ua + 0x7fffu + ((ua >> 16) & 1u)) >> 16;   // RNE to bf16
  ub = (ub + 0x7fffu + ((ub >> 16) & 1u)) >> 16;
  return (ua & 0xffffu) | (ub << 16);
}

// Read 8 floats at stride 64 (one fragment's k-run), pack to bf16x8.
__device__ __forceinline__ bf16x8 ldsfrag(const float* p) {
  float f0 = p[0*64], f1 = p[1*64], f2 = p[2*64], f3 = p[3*64];
  float f4 = p[4*64], f5 = p[5*64], f6 = p[6*64], f7 = p[7*64];
  uint4 q;
  q.x = bf16pk(f0, f1); q.y = bf16pk(f2, f3);
  q.z = bf16pk(f4, f5); q.w = bf16pk(f6, f7);
  return __builtin_bit_cast(bf16x8, q);
}

#define MFMA(a, b, c) __builtin_amdgcn_mfma_f32_32x32x16_bf16((a), (b), (c), 0, 0, 0)

// LDS: main loop uses [0..8192): 4 waves x 2048 floats (R[16][64] ++ I[16][64]).
// Epilogue reuses [0..8320) as two 64x65 padded mats. Block LDS = 33.3 KB
// -> 4 blocks/CU (133 KB), 16 waves/CU.
template<int CHUNKS>
__global__ __launch_bounds__(256, 4) void gram_partial(
    const float* __restrict__ R, const float* __restrict__ I,
    float* __restrict__ ws)
{
  constexpr int SCHUNK = SEQ / CHUNKS;
  constexpr int ROUNDS = SCHUNK / 64;       // 4 waves x 16 s-rows per round
  __shared__ float lds[8320];
  const int tid  = threadIdx.x;
  const int wave = tid >> 6;
  const int lane = tid & 63;
  const int l31  = lane & 31;
  const int lhi  = lane >> 5;
  const int b = blockIdx.x & 31;
  const int c = blockIdx.x >> 5;

  float* myb = lds + wave * 2048;           // wave-private 8 KB
  const size_t g0 = (size_t)b * (SEQ * DD) + (size_t)(c * SCHUNK + wave * 16) * DD;
  const float* gR = R + g0;
  const float* gI = I + g0;

  f32x16 aS0 = {}, aS1 = {}, aS2 = {};            // S(0,0) S(0,32) S(32,32)
  f32x16 aM0 = {}, aM1 = {}, aM2 = {}, aM3 = {};  // M(0,0) M(0,32) M(32,0) M(32,32)

  for (int r = 0; r < ROUNDS; ++r) {
    const float* gr = gR + (size_t)r * (64 * DD);
    const float* gi = gI + (size_t)r * (64 * DD);
    // stage 16 s-rows of R and I: 8 x 1KB fire-and-forget DMAs
    #pragma unroll
    for (int t = 0; t < 4; ++t) {
      GLD_LDS16(gr + t * 256 + lane * 4, myb + t * 256);
      GLD_LDS16(gi + t * 256 + lane * 4, myb + 1024 + t * 256);
    }
    asm volatile("s_waitcnt vmcnt(0)" ::: "memory");
    const float* pR = myb + (lhi * 8) * 64 + l31;
    const float* pI = pR + 1024;
    bf16x8 r0  = ldsfrag(pR),  r32 = ldsfrag(pR + 32);
    bf16x8 i0  = ldsfrag(pI),  i32 = ldsfrag(pI + 32);
    aS0 = MFMA(r0,  r0,  aS0);  aS0 = MFMA(i0,  i0,  aS0);
    aS1 = MFMA(r0,  r32, aS1);  aS1 = MFMA(i0,  i32, aS1);
    aS2 = MFMA(r32, r32, aS2);  aS2 = MFMA(i32, i32, aS2);
    aM0 = MFMA(r0,  i0,  aM0);
    aM1 = MFMA(r0,  i32, aM1);
    aM2 = MFMA(r32, i0,  aM2);
    aM3 = MFMA(r32, i32, aM3);
    // LDS reads must retire before next round's DMA overwrites the buffer
    asm volatile("s_waitcnt lgkmcnt(0)" ::: "memory");
  }

  // ---- epilogue: sum wave quads in padded LDS, emit block partials ----
  __syncthreads();
  float* Sp = lds;                        // 64 x 65
  float* Mp = lds + 4160;                 // 64 x 65
  for (int e = tid; e < 8320; e += 256) lds[e] = 0.0f;
  __syncthreads();
  #pragma unroll 1
  for (int w = 0; w < 4; ++w) {
    if (wave == w) {
      #pragma unroll
      for (int r = 0; r < 16; ++r) {
        const int ii = (r & 3) + 8 * (r >> 2) + 4 * lhi;
        const int jj = l31;
        Sp[ii * 65 + jj]              += aS0[r];
        Sp[ii * 65 + 32 + jj]         += aS1[r];
        Sp[(32 + ii) * 65 + 32 + jj]  += aS2[r];
        Mp[ii * 65 + jj]              += aM0[r];
        Mp[ii * 65 + 32 + jj]         += aM1[r];
        Mp[(32 + ii) * 65 + jj]       += aM2[r];
        Mp[(32 + ii) * 65 + 32 + jj]  += aM3[r];
      }
    }
    __syncthreads();
  }
  float* wsS = ws + ((size_t)(c * 32 + b) * 2) * 4096;
  float* wsM = wsS + 4096;
  #pragma unroll
  for (int k = 0; k < 16; ++k) {
    const int e = tid + 256 * k;
    const int i = e >> 6, j = e & 63;
    const float sv = (i >= 32 && j < 32) ? Sp[j * 65 + i] : Sp[i * 65 + j];
    wsS[e] = sv;                                  // symmetric mirror
    wsM[e] = Mp[i * 65 + j] - Mp[j * 65 + i];     // antisymmetrize
  }
}

// Sum CHUNKS chunk-partials, scale 1/S. 1024 blocks -> 16 waves/CU;
// each output float4 is summed by 4 threads (CHUNKS/4 loads each) + LDS fold.
template<int CHUNKS>
__global__ __launch_bounds__(256) void gram_reduce(
    const float4* __restrict__ ws, float4* __restrict__ out)
{
  __shared__ float4 red[256];
  const int t = threadIdx.x;
  const int o = blockIdx.x * 64 + (t & 63);       // of 65536 float4s
  const int q = t >> 6;                           // chunk quarter
  const int kind = o >> 15;
  const int rem  = o & 32767;
  const int b    = rem >> 10;
  const int e    = rem & 1023;
  float sx = 0.f, sy = 0.f, sz = 0.f, sw = 0.f;
  #pragma unroll
  for (int cc = 0; cc < CHUNKS / 4; ++cc) {
    const int c = q * (CHUNKS / 4) + cc;
    float4 v = ws[((size_t)(c * 32 + b) * 2 + kind) * 1024 + e];
    sx += v.x; sy += v.y; sz += v.z; sw += v.w;
  }
  float4 p; p.x = sx; p.y = sy; p.z = sz; p.w = sw;
  red[t] = p;
  __syncthreads();
  if (t < 64) {
    const float inv = 1.0f / (float)SEQ;
    float4 a = red[t], b2 = red[t + 64], c2 = red[t + 128], d = red[t + 192];
    float4 r;
    r.x = (a.x + b2.x + c2.x + d.x) * inv;
    r.y = (a.y + b2.y + c2.y + d.y) * inv;
    r.z = (a.z + b2.z + c2.z + d.z) * inv;
    r.w = (a.w + b2.w + c2.w + d.w) * inv;
    out[o] = r;
  }
}

extern "C" void kernel_launch(void* const* d_in, const int* in_sizes, int n_in,
                              void* d_out, int out_size, void* d_ws, size_t ws_size,
                              hipStream_t stream) {
  const float* R = (const float*)d_in[0];
  const float* I = (const float*)d_in[1];
  float* out = (float*)d_out;
  float* ws  = (float*)d_ws;

  const size_t need32 = (size_t)32 * 32 * 2 * 4096 * 4;   // 33.6 MB
  if (ws_size >= need32) {
    gram_partial<32><<<BATCH * 32, 256, 0, stream>>>(R, I, ws);
    gram_reduce<32><<<1024, 256, 0, stream>>>((const float4*)ws, (float4*)out);
  } else {
    gram_partial<16><<<BATCH * 16, 256, 0, stream>>>(R, I, ws);
    gram_reduce<16><<<512, 256, 0, stream>>>((const float4*)ws, (float4*)out);
  }
}

// Round 7
// 163.973 us; speedup vs baseline: 1.4700x; 1.4700x over previous
//
#include <hip/hip_runtime.h>

// ComplexMixture: B=32, S=8192, D=64, fp32 in/out.
// out_real = (R^T R + I^T I)/S ; out_imag = (R^T I - (R^T I)^T)/S
// R7: wave-private slab pipeline with float4 VGPR loads (m13 pattern) at
// launch_bounds(256,2) so the compiler KEEPS prefetch hoisted (R2/R4 failed
// at 128-reg budget; R5/R6 DMA serialized). 7 quads/wave, no loop barriers.

#define BATCH  32
#define SEQ    8192
#define DD     64
#define CHUNKS 16
#define SCHUNK (SEQ / CHUNKS)   // 512
#define ROUNDS 8                // per wave: 8 rounds x 16 s-rows (4 waves interleaved)

typedef __bf16 bf16x8 __attribute__((ext_vector_type(8)));
typedef float  f32x16 __attribute__((ext_vector_type(16)));

__device__ __forceinline__ unsigned bf16pk(float a, float b) {
  unsigned ua = __builtin_bit_cast(unsigned, a);
  unsigned ub = __builtin_bit_cast(unsigned, b);
  ua = (ua + 0x7fffu + ((ua >> 16) & 1u)) >> 16;   // RNE to bf16
  ub = (ub + 0x7fffu + ((ub >> 16) & 1u)) >> 16;
  return (ua & 0xffffu) | (ub << 16);
}

// Read 8 floats at stride 64 (one fragment's k-run), pack to bf16x8.
__device__ __forceinline__ bf16x8 ldsfrag(const float* p) {
  float f0 = p[0*64], f1 = p[1*64], f2 = p[2*64], f3 = p[3*64];
  float f4 = p[4*64], f5 = p[5*64], f6 = p[6*64], f7 = p[7*64];
  uint4 q;
  q.x = bf16pk(f0, f1); q.y = bf16pk(f2, f3);
  q.z = bf16pk(f4, f5); q.w = bf16pk(f6, f7);
  return __builtin_bit_cast(bf16x8, q);
}

#define MFMA(a, b, c) __builtin_amdgcn_mfma_f32_32x32x16_bf16((a), (b), (c), 0, 0, 0)

// LDS: loop uses 4 waves x 2048 floats (slab = R[16][64] ++ I[16][64] fp32,
// 8 KB/wave, single-buffered -- prefetch lives in VGPRs, not LDS).
// Epilogue reuses [0..8320) as two 64x65 padded mats. Block LDS = 33.3 KB.
__global__ __launch_bounds__(256, 2) void gram_partial(
    const float* __restrict__ R, const float* __restrict__ I,
    float* __restrict__ ws)
{
  __shared__ float lds[8320];
  const int tid  = threadIdx.x;
  const int wave = tid >> 6;
  const int lane = tid & 63;
  const int l31  = lane & 31;
  const int lhi  = lane >> 5;
  const int b = blockIdx.x & 31;
  const int c = blockIdx.x >> 5;

  float*  slab   = lds + wave * 2048;            // [R 1024 floats][I 1024 floats]
  float4* slabR4 = (float4*)slab;
  float4* slabI4 = (float4*)(slab + 1024);

  // wave w, round r covers s-rows: c*512 + r*64 + w*16 .. +16 (waves interleaved)
  const size_t gbase = (size_t)b * (SEQ * DD) + (size_t)(c * SCHUNK + wave * 16) * DD;
  const float4* gR4 = (const float4*)(R + gbase);
  const float4* gI4 = (const float4*)(I + gbase);
  // per round advance = 64 rows = 1024 float4s

  f32x16 aS0 = {}, aS1 = {}, aS2 = {};            // S(0,0) S(0,32) S(32,32)
  f32x16 aM0 = {}, aM1 = {}, aM2 = {}, aM3 = {};  // M(0,0) M(0,32) M(32,0) M(32,32)

  float4 bA[8], bB[8];                            // ping-pong prefetch (16 KB in flight)

  auto LOAD = [&](float4 (&buf)[8], int r) {
    const size_t o = (size_t)r * 1024 + lane;     // slab float4 idx == t*64+lane
    #pragma unroll
    for (int t = 0; t < 4; ++t) {
      buf[t]     = gR4[o + t * 64];
      buf[4 + t] = gI4[o + t * 64];
    }
  };

  auto STEP = [&](float4 (&cur)[8]) {
    #pragma unroll
    for (int t = 0; t < 4; ++t) {                 // 8 x ds_write_b128
      slabR4[t * 64 + lane] = cur[t];
      slabI4[t * 64 + lane] = cur[4 + t];
    }
    asm volatile("s_waitcnt lgkmcnt(0)" ::: "memory");   // writes visible to own reads
    const float* pR = slab + (lhi * 8) * 64 + l31;
    const float* pI = pR + 1024;
    bf16x8 r0  = ldsfrag(pR),  r32 = ldsfrag(pR + 32);
    bf16x8 i0  = ldsfrag(pI),  i32 = ldsfrag(pI + 32);
    aS0 = MFMA(r0,  r0,  aS0);  aS0 = MFMA(i0,  i0,  aS0);
    aS1 = MFMA(r0,  r32, aS1);  aS1 = MFMA(i0,  i32, aS1);
    aS2 = MFMA(r32, r32, aS2);  aS2 = MFMA(i32, i32, aS2);
    aM0 = MFMA(r0,  i0,  aM0);
    aM1 = MFMA(r0,  i32, aM1);
    aM2 = MFMA(r32, i0,  aM2);
    aM3 = MFMA(r32, i32, aM3);
  };

  LOAD(bA, 0);
  #pragma unroll
  for (int r = 0; r < ROUNDS; r += 2) {
    if (r + 1 < ROUNDS) LOAD(bB, r + 1);
    STEP(bA);
    if (r + 2 < ROUNDS) LOAD(bA, r + 2);
    if (r + 1 < ROUNDS) STEP(bB);
  }

  // ---- epilogue: sum wave quads in padded LDS, emit block partials ----
  __syncthreads();
  float* Sp = lds;                        // 64 x 65
  float* Mp = lds + 4160;                 // 64 x 65
  for (int e = tid; e < 8320; e += 256) lds[e] = 0.0f;
  __syncthreads();
  #pragma unroll 1
  for (int w = 0; w < 4; ++w) {
    if (wave == w) {
      #pragma unroll
      for (int r = 0; r < 16; ++r) {
        const int ii = (r & 3) + 8 * (r >> 2) + 4 * lhi;
        const int jj = l31;
        Sp[ii * 65 + jj]              += aS0[r];
        Sp[ii * 65 + 32 + jj]         += aS1[r];
        Sp[(32 + ii) * 65 + 32 + jj]  += aS2[r];
        Mp[ii * 65 + jj]              += aM0[r];
        Mp[ii * 65 + 32 + jj]         += aM1[r];
        Mp[(32 + ii) * 65 + jj]       += aM2[r];
        Mp[(32 + ii) * 65 + 32 + jj]  += aM3[r];
      }
    }
    __syncthreads();
  }
  float* wsS = ws + ((size_t)(c * 32 + b) * 2) * 4096;
  float* wsM = wsS + 4096;
  #pragma unroll
  for (int k = 0; k < 16; ++k) {
    const int e = tid + 256 * k;
    const int i = e >> 6, j = e & 63;
    const float sv = (i >= 32 && j < 32) ? Sp[j * 65 + i] : Sp[i * 65 + j];
    wsS[e] = sv;                                  // symmetric mirror
    wsM[e] = Mp[i * 65 + j] - Mp[j * 65 + i];     // antisymmetrize
  }
}

// Sum CHUNKS chunk-partials, scale 1/S. 1024 blocks x 64 float4 outputs;
// each output summed by 4 threads (CHUNKS/4 chunks each) + LDS fold.
__global__ __launch_bounds__(256) void gram_reduce(
    const float4* __restrict__ ws, float4* __restrict__ out)
{
  __shared__ float4 red[256];
  const int t = threadIdx.x;
  const int o = blockIdx.x * 64 + (t & 63);       // of 65536 float4s
  const int q = t >> 6;                           // chunk quarter
  const int kind = o >> 15;
  const int rem  = o & 32767;
  const int b    = rem >> 10;
  const int e    = rem & 1023;
  float sx = 0.f, sy = 0.f, sz = 0.f, sw = 0.f;
  #pragma unroll
  for (int cc = 0; cc < CHUNKS / 4; ++cc) {
    const int c = q * (CHUNKS / 4) + cc;
    float4 v = ws[((size_t)(c * 32 + b) * 2 + kind) * 1024 + e];
    sx += v.x; sy += v.y; sz += v.z; sw += v.w;
  }
  float4 p; p.x = sx; p.y = sy; p.z = sz; p.w = sw;
  red[t] = p;
  __syncthreads();
  if (t < 64) {
    const float inv = 1.0f / (float)SEQ;
    float4 a = red[t], b2 = red[t + 64], c2 = red[t + 128], d = red[t + 192];
    float4 r;
    r.x = (a.x + b2.x + c2.x + d.x) * inv;
    r.y = (a.y + b2.y + c2.y + d.y) * inv;
    r.z = (a.z + b2.z + c2.z + d.z) * inv;
    r.w = (a.w + b2.w + c2.w + d.w) * inv;
    out[o] = r;
  }
}

extern "C" void kernel_launch(void* const* d_in, const int* in_sizes, int n_in,
                              void* d_out, int out_size, void* d_ws, size_t ws_size,
                              hipStream_t stream) {
  const float* R = (const float*)d_in[0];
  const float* I = (const float*)d_in[1];
  float* out = (float*)d_out;
  float* ws  = (float*)d_ws;   // 512 * 8192 * 4 B = 16.8 MB

  gram_partial<<<BATCH * CHUNKS, 256, 0, stream>>>(R, I, ws);
  gram_reduce<<<1024, 256, 0, stream>>>((const float4*)ws, (float4*)out);
}